// Round 3
// baseline (123.671 us; speedup 1.0000x reference)
//
#include <hip/hip_runtime.h>
#include <hip/hip_fp16.h>
#include <math.h>

// Problem constants (match reference)
#define BB 4096
#define LL 128
#define DD 64
#define VV 50257

typedef _Float16 h2_t __attribute__((ext_vector_type(2)));

// fp16x2 dot-accumulate: one v_dot2_f32_f16 where available.
__device__ __forceinline__ float dot2acc(unsigned a, unsigned b, float c) {
#if __has_builtin(__builtin_amdgcn_fdot2)
    return __builtin_amdgcn_fdot2(__builtin_bit_cast(h2_t, a),
                                  __builtin_bit_cast(h2_t, b), c, false);
#else
    const float2 fa = __half22float2(*(const __half2*)&a);
    const float2 fb = __half22float2(*(const __half2*)&b);
    return fmaf(fa.x, fb.x, fmaf(fa.y, fb.y, c));
#endif
}

__device__ __forceinline__ float2 cvt2(unsigned raw) {
    return __half22float2(*(const __half2*)&raw);
}

__device__ __forceinline__ unsigned pack_h2(float a, float b) {
    union { __half2 h; unsigned u; } p;
    p.h = __floats2half2_rn(a, b);
    return p.u;
}

// ---------------------------------------------------------------------------
// Kernel 1: stream-convert both fp32 tables into ONE fused fp16 table:
//   row id occupies 256 B = mu[id] (128 B) followed by feat[id] (128 B).
// 12.9 MB total -> L2/L3-friendly; one base address per gathered row.
// ---------------------------------------------------------------------------
__global__ __launch_bounds__(256) void convert_fused_kernel(
    const float* __restrict__ mu, const float* __restrict__ feat,
    __half* __restrict__ out)
{
    const int total = VV * 16;              // 16-byte chunks in fused table
    for (int i = blockIdx.x * blockDim.x + threadIdx.x; i < total;
         i += gridDim.x * blockDim.x) {
        const int row = i >> 4;
        const int c   = i & 15;
        const float* src = (c < 8) ? (mu   + row * DD + c * 8)
                                   : (feat + row * DD + (c - 8) * 8);
        const float4 s0 = ((const float4*)src)[0];
        const float4 s1 = ((const float4*)src)[1];
        uint4 o;
        o.x = pack_h2(s0.x, s0.y); o.y = pack_h2(s0.z, s0.w);
        o.z = pack_h2(s1.x, s1.y); o.w = pack_h2(s1.z, s1.w);
        ((uint4*)out)[i] = o;               // byte offset i*16 == row*256 + c*16
    }
}

// ---------------------------------------------------------------------------
// Kernel 2: Round-0 two-round structure (mu gather in phase 2; feat gather
// overlapped with score compute in phase 3, overwriting v[]), fused table,
// and OCCUPANCY as the lever: no held voff[] (address recomputed from s_cid
// -- 1 LDS read + 2 VALU), __launch_bounds__(256,8) caps VGPR at 64 ->
// 8 blocks/CU, 32 waves/CU (vs 16 in rounds 1-2). Latency-hiding for the
// random L3 gathers comes from TLP, which rounds 1-2 showed beats ILP here.
// ---------------------------------------------------------------------------
__global__ __launch_bounds__(256, 8) void softmax_attn_cos_kernel(
    const int* __restrict__ ids_a, const int* __restrict__ mask_a,
    const int* __restrict__ ids_b, const int* __restrict__ mask_b,
    const __half* __restrict__ fused_table, float* __restrict__ out)
{
    __shared__ int      s_cid[2][LL];     // compacted unmasked ids
    __shared__ int      s_cnt[2][2];      // per-side, per-half unmasked counts
    __shared__ unsigned s_qh[2][32];      // q packed as 32 half2
    __shared__ float4   s_qp[2][2][16];   // q partials
    __shared__ float    s_sc[2][LL];      // scores -> exp weights (compacted)
    __shared__ float4   s_op[2][2][16];
    __shared__ float    s_mean[2][DD];
    __shared__ float    s_sum[2];

    const int tid  = threadIdx.x;
    const int lane = tid & 63;
    const int wave = tid >> 6;        // 0..3
    const int side = wave >> 1;       // 0: a, 1: b
    const int wsub = wave & 1;        // which half (rows / groups parity)
    const int r8   = lane >> 3;       // 0..7 row subgroup
    const int c8   = lane & 7;        // 16-B chunk (8 halves) within a row
    const int b    = blockIdx.x;

    // ---- phase 1: load this wave's 64 rows; ballot-compact within wave ----
    {
        const int l = wsub * 64 + lane;
        const int* idp = side ? ids_b  : ids_a;
        const int* mp  = side ? mask_b : mask_a;
        const int id = idp[b * LL + l];
        const int m  = mp[b * LL + l];
        const unsigned long long bal = __ballot(m != 0);
        if (lane == 0) s_cnt[side][wsub] = __popcll(bal);
        const int rank = __popcll(bal & ((1ull << lane) - 1ull));
        __syncthreads();
        const int offset = wsub ? s_cnt[side][0] : 0;
        if (m) s_cid[side][offset + rank] = id;
        if (s_cnt[side][0] + s_cnt[side][1] == 0)
            s_cid[side][l] = id;                   // all-masked fallback
    }
    __syncthreads();

    const int   nm  = s_cnt[side][0] + s_cnt[side][1];
    const int   nme = (nm == 0) ? 128 : nm;        // effective compacted length
    const int   G   = (nme + 7) >> 3;              // 8-row groups

    // ---- phase 2: gather compacted mu half-rows, q partials;
    //      wave-uniform skip of groups >= G ----
    uint4 v[8];
    {
        float4 qa = make_float4(0.f, 0.f, 0.f, 0.f);
        float4 qb = make_float4(0.f, 0.f, 0.f, 0.f);
        #pragma unroll
        for (int it = 0; it < 8; ++it) {
            v[it] = make_uint4(0u, 0u, 0u, 0u);
            const int g = 2 * it + wsub;
            if (g < G) {                            // wave-uniform branch
                const int p  = g * 8 + r8;
                const int id = (p < nme) ? s_cid[side][p] : 0;
                const unsigned byo = ((unsigned)id << 8) + ((unsigned)c8 << 4);
                v[it] = *(const uint4*)((const char*)fused_table + byo);
                if (p < nm) {                       // live rows only (nm==0: none)
                    const float2 f0 = cvt2(v[it].x), f1 = cvt2(v[it].y);
                    const float2 f2 = cvt2(v[it].z), f3 = cvt2(v[it].w);
                    qa.x += f0.x; qa.y += f0.y; qa.z += f1.x; qa.w += f1.y;
                    qb.x += f2.x; qb.y += f2.y; qb.z += f3.x; qb.w += f3.y;
                }
            }
        }
        #pragma unroll
        for (int off = 8; off <= 32; off <<= 1) {   // sum the 8 row-groups
            qa.x += __shfl_xor(qa.x, off, 64); qa.y += __shfl_xor(qa.y, off, 64);
            qa.z += __shfl_xor(qa.z, off, 64); qa.w += __shfl_xor(qa.w, off, 64);
            qb.x += __shfl_xor(qb.x, off, 64); qb.y += __shfl_xor(qb.y, off, 64);
            qb.z += __shfl_xor(qb.z, off, 64); qb.w += __shfl_xor(qb.w, off, 64);
        }
        if (lane < 8) {
            s_qp[side][wsub][2 * c8]     = qa;
            s_qp[side][wsub][2 * c8 + 1] = qb;
        }
    }
    __syncthreads();

    // ---- q = (masked mean) packed as half2; denom from counts ----
    if (tid < 128) {
        const int si = tid >> 6;
        const int dd = tid & 63;
        if (dd < 16) {
            const float dn = fmaxf((float)(s_cnt[si][0] + s_cnt[si][1]), 1.0f);
            const float rd = 1.0f / dn;
            const float4 q0 = s_qp[si][0][dd], q1 = s_qp[si][1][dd];
            s_qh[si][2 * dd]     = pack_h2((q0.x + q1.x) * rd, (q0.y + q1.y) * rd);
            s_qh[si][2 * dd + 1] = pack_h2((q0.z + q1.z) * rd, (q0.w + q1.w) * rd);
        }
    }
    __syncthreads();

    // ---- phase 3: scores from held regs (v_dot2) + feat prefetch
    //      (address recomputed from s_cid; feat chunk at +128) ----
    {
        const uint4 qq = ((const uint4*)&s_qh[side][0])[c8];
        #pragma unroll
        for (int it = 0; it < 8; ++it) {
            const int g = 2 * it + wsub;
            if (g < G) {
                const int p  = g * 8 + r8;
                const int id = (p < nme) ? s_cid[side][p] : 0;
                const unsigned byo = ((unsigned)id << 8) + ((unsigned)c8 << 4);
                const uint4 nf = *(const uint4*)((const char*)fused_table + byo + 128);
                float sp = dot2acc(v[it].x, qq.x, 0.f);
                sp = dot2acc(v[it].y, qq.y, sp);
                sp = dot2acc(v[it].z, qq.z, sp);
                sp = dot2acc(v[it].w, qq.w, sp);
                #pragma unroll
                for (int off = 1; off <= 4; off <<= 1)
                    sp += __shfl_xor(sp, off, 64);   // reduce within 8-lane group
                if (c8 == 0 && p < nme) s_sc[side][p] = sp;
                v[it] = nf;
            }
        }
    }
    __syncthreads();

    // ---- phase 4: softmax over compacted scores (waves with wsub==0) ----
    if (wsub == 0) {
        const float s1 = (lane      < nme) ? s_sc[side][lane]      : -1e9f;
        const float s2 = (lane + 64 < nme) ? s_sc[side][lane + 64] : -1e9f;
        float mx = fmaxf(s1, s2);
        #pragma unroll
        for (int off = 32; off; off >>= 1) mx = fmaxf(mx, __shfl_xor(mx, off, 64));
        const float e1 = expf(s1 - mx), e2 = expf(s2 - mx);   // padding -> 0
        s_sc[side][lane] = e1; s_sc[side][lane + 64] = e2;
        float sm = e1 + e2;
        #pragma unroll
        for (int off = 32; off; off >>= 1) sm += __shfl_xor(sm, off, 64);
        if (lane == 0) s_sum[side] = sm;
    }
    __syncthreads();

    // ---- phase 5: attn-weighted sum from held feat regs ----
    {
        float4 oa = make_float4(0.f, 0.f, 0.f, 0.f);
        float4 ob = make_float4(0.f, 0.f, 0.f, 0.f);
        #pragma unroll
        for (int it = 0; it < 8; ++it) {
            const int g = 2 * it + wsub;
            if (g < G) {
                const int p = g * 8 + r8;
                const float w = (p < nme) ? s_sc[side][p] : 0.f;
                const float2 f0 = cvt2(v[it].x), f1 = cvt2(v[it].y);
                const float2 f2 = cvt2(v[it].z), f3 = cvt2(v[it].w);
                oa.x = fmaf(f0.x, w, oa.x); oa.y = fmaf(f0.y, w, oa.y);
                oa.z = fmaf(f1.x, w, oa.z); oa.w = fmaf(f1.y, w, oa.w);
                ob.x = fmaf(f2.x, w, ob.x); ob.y = fmaf(f2.y, w, ob.y);
                ob.z = fmaf(f3.x, w, ob.z); ob.w = fmaf(f3.y, w, ob.w);
            }
        }
        #pragma unroll
        for (int off = 8; off <= 32; off <<= 1) {
            oa.x += __shfl_xor(oa.x, off, 64); oa.y += __shfl_xor(oa.y, off, 64);
            oa.z += __shfl_xor(oa.z, off, 64); oa.w += __shfl_xor(oa.w, off, 64);
            ob.x += __shfl_xor(ob.x, off, 64); ob.y += __shfl_xor(ob.y, off, 64);
            ob.z += __shfl_xor(ob.z, off, 64); ob.w += __shfl_xor(ob.w, off, 64);
        }
        if (lane < 8) {
            s_op[side][wsub][2 * c8]     = oa;
            s_op[side][wsub][2 * c8 + 1] = ob;
        }
    }
    __syncthreads();

    // ---- combine halves -> mean vectors ----
    if (tid < 32) {
        const int si = tid >> 4, cc = tid & 15;
        const float inv = 1.0f / s_sum[si];
        const float4 o0 = s_op[si][0][cc], o1 = s_op[si][1][cc];
        float4 o;
        o.x = (o0.x + o1.x) * inv; o.y = (o0.y + o1.y) * inv;
        o.z = (o0.z + o1.z) * inv; o.w = (o0.w + o1.w) * inv;
        ((float4*)&s_mean[si][0])[cc] = o;
    }
    __syncthreads();

    // ---- cosine similarity * 5 (wave 0) ----
    if (tid < 64) {
        const float a = s_mean[0][tid], c = s_mean[1][tid];
        float dt = a * c, na = a * a, nb = c * c;
        #pragma unroll
        for (int off = 32; off; off >>= 1) {
            dt += __shfl_xor(dt, off, 64);
            na += __shfl_xor(na, off, 64);
            nb += __shfl_xor(nb, off, 64);
        }
        if (tid == 0) {
            const float denom = fmaxf(sqrtf(na), 1e-8f) * fmaxf(sqrtf(nb), 1e-8f);
            out[b] = 5.0f * dt / denom;
        }
    }
}

extern "C" void kernel_launch(void* const* d_in, const int* in_sizes, int n_in,
                              void* d_out, int out_size, void* d_ws, size_t ws_size,
                              hipStream_t stream) {
    const int*   ids_a  = (const int*)d_in[0];
    const int*   mask_a = (const int*)d_in[1];
    const int*   ids_b  = (const int*)d_in[2];
    const int*   mask_b = (const int*)d_in[3];
    const float* mu     = (const float*)d_in[4];
    const float* feat   = (const float*)d_in[5];
    float* out = (float*)d_out;

    __half* ws_fused = (__half*)d_ws;   // V rows x 256 B (mu||feat) ~ 12.9 MB

    convert_fused_kernel<<<2048, 256, 0, stream>>>(mu, feat, ws_fused);
    softmax_attn_cos_kernel<<<BB, 256, 0, stream>>>(
        ids_a, mask_a, ids_b, mask_b, ws_fused, out);
}

// Round 5
// 118.529 us; speedup vs baseline: 1.0434x; 1.0434x over previous
//
#include <hip/hip_runtime.h>
#include <hip/hip_fp16.h>
#include <math.h>

// Problem constants (match reference)
#define BB 4096
#define LL 128
#define DD 64
#define VV 50257
#define IPB 2                 // batch items per block
#define NBLK (BB / IPB)       // 2048 blocks

typedef _Float16 h2_t __attribute__((ext_vector_type(2)));

// fp16x2 dot-accumulate: one v_dot2_f32_f16 where available.
__device__ __forceinline__ float dot2acc(unsigned a, unsigned b, float c) {
#if __has_builtin(__builtin_amdgcn_fdot2)
    return __builtin_amdgcn_fdot2(__builtin_bit_cast(h2_t, a),
                                  __builtin_bit_cast(h2_t, b), c, false);
#else
    const float2 fa = __half22float2(*(const __half2*)&a);
    const float2 fb = __half22float2(*(const __half2*)&b);
    return fmaf(fa.x, fb.x, fmaf(fa.y, fb.y, c));
#endif
}

__device__ __forceinline__ float2 cvt2(unsigned raw) {
    return __half22float2(*(const __half2*)&raw);
}

__device__ __forceinline__ unsigned pack_h2(float a, float b) {
    union { __half2 h; unsigned u; } p;
    p.h = __floats2half2_rn(a, b);
    return p.u;
}

// ---------------------------------------------------------------------------
// Kernel 1: stream-convert both fp32 tables into ONE fused fp16 table:
//   row id occupies 256 B = mu[id] (128 B) followed by feat[id] (128 B).
// ---------------------------------------------------------------------------
__global__ __launch_bounds__(256) void convert_fused_kernel(
    const float* __restrict__ mu, const float* __restrict__ feat,
    __half* __restrict__ out)
{
    const int total = VV * 16;              // 16-byte chunks in fused table
    for (int i = blockIdx.x * blockDim.x + threadIdx.x; i < total;
         i += gridDim.x * blockDim.x) {
        const int row = i >> 4;
        const int c   = i & 15;
        const float* src = (c < 8) ? (mu   + row * DD + c * 8)
                                   : (feat + row * DD + (c - 8) * 8);
        const float4 s0 = ((const float4*)src)[0];
        const float4 s1 = ((const float4*)src)[1];
        uint4 o;
        o.x = pack_h2(s0.x, s0.y); o.y = pack_h2(s0.z, s0.w);
        o.z = pack_h2(s1.x, s1.y); o.w = pack_h2(s1.z, s1.w);
        ((uint4*)out)[i] = o;               // byte offset i*16 == row*256 + c*16
    }
}

// ---------------------------------------------------------------------------
// Kernel 2: GRID-HALVING experiment (resubmit of Round 4; container flake).
// 2 batch items per 512-thread block (waves 0-3: item 0, waves 4-7: item 1),
// 2048 blocks total. Per-item structure is the best-known Round-0 shape:
// mask compaction, two-round gather (mu held in v[8] with held voff[8];
// feat prefetched during score compute, overwriting v[]), fused fp16 table.
// Tests per-block overhead: every internal knob (occupancy/MLP/granule)
// left the main kernel at ~44 us.
// __launch_bounds__(512,6): 3 blocks/CU (24 waves), VGPR cap ~85 -> the
// ~64-VGPR body fits WITHOUT the spill that poisoned Round 3.
// ---------------------------------------------------------------------------
__global__ __launch_bounds__(512, 6) void softmax_attn_cos_kernel(
    const int* __restrict__ ids_a, const int* __restrict__ mask_a,
    const int* __restrict__ ids_b, const int* __restrict__ mask_b,
    const __half* __restrict__ fused_table, float* __restrict__ out)
{
    __shared__ int      s_cid[IPB][2][LL];     // compacted unmasked ids
    __shared__ int      s_cnt[IPB][2][2];      // per-item/side/half counts
    __shared__ unsigned s_qh[IPB][2][32];      // q packed as 32 half2
    __shared__ float4   s_qp[IPB][2][2][16];   // q partials
    __shared__ float    s_sc[IPB][2][LL];      // scores -> exp weights
    __shared__ float4   s_op[IPB][2][2][16];
    __shared__ float    s_mean[IPB][2][DD];
    __shared__ float    s_sum[IPB][2];

    const int tid  = threadIdx.x;
    const int lane = tid & 63;
    const int wave = tid >> 6;        // 0..7
    const int item = wave >> 2;       // 0..1
    const int tid8 = tid & 255;       // tid within item
    const int side = (wave >> 1) & 1; // 0: a, 1: b
    const int wsub = wave & 1;        // which half (rows / groups parity)
    const int r8   = lane >> 3;       // 0..7 row subgroup
    const int c8   = lane & 7;        // 16-B chunk (8 halves) within a row
    const int b    = blockIdx.x * IPB + item;

    // ---- phase 1: load this wave's 64 rows; ballot-compact within wave ----
    {
        const int l = wsub * 64 + lane;
        const int* idp = side ? ids_b  : ids_a;
        const int* mp  = side ? mask_b : mask_a;
        const int id = idp[b * LL + l];
        const int m  = mp[b * LL + l];
        const unsigned long long bal = __ballot(m != 0);
        if (lane == 0) s_cnt[item][side][wsub] = __popcll(bal);
        const int rank = __popcll(bal & ((1ull << lane) - 1ull));
        __syncthreads();
        const int offset = wsub ? s_cnt[item][side][0] : 0;
        if (m) s_cid[item][side][offset + rank] = id;
        if (s_cnt[item][side][0] + s_cnt[item][side][1] == 0)
            s_cid[item][side][l] = id;             // all-masked fallback
    }
    __syncthreads();

    const int   nm  = s_cnt[item][side][0] + s_cnt[item][side][1];
    const int   nme = (nm == 0) ? 128 : nm;        // effective compacted length
    const int   G   = (nme + 7) >> 3;              // 8-row groups

    // ---- phase 2: gather compacted mu half-rows (held voff), q partials;
    //      wave-uniform skip of groups >= G ----
    uint4 v[8];
    unsigned voff[8];
    {
        float4 qa = make_float4(0.f, 0.f, 0.f, 0.f);
        float4 qb = make_float4(0.f, 0.f, 0.f, 0.f);
        #pragma unroll
        for (int it = 0; it < 8; ++it) {
            v[it] = make_uint4(0u, 0u, 0u, 0u);
            voff[it] = 0u;
            const int g = 2 * it + wsub;
            if (g < G) {                            // wave-uniform branch
                const int p  = g * 8 + r8;
                const int id = (p < nme) ? s_cid[item][side][p] : 0;
                voff[it] = ((unsigned)id << 8) + ((unsigned)c8 << 4);
                v[it] = *(const uint4*)((const char*)fused_table + voff[it]);
                if (p < nm) {                       // live rows only
                    const float2 f0 = cvt2(v[it].x), f1 = cvt2(v[it].y);
                    const float2 f2 = cvt2(v[it].z), f3 = cvt2(v[it].w);
                    qa.x += f0.x; qa.y += f0.y; qa.z += f1.x; qa.w += f1.y;
                    qb.x += f2.x; qb.y += f2.y; qb.z += f3.x; qb.w += f3.y;
                }
            }
        }
        #pragma unroll
        for (int off = 8; off <= 32; off <<= 1) {   // sum the 8 row-groups
            qa.x += __shfl_xor(qa.x, off, 64); qa.y += __shfl_xor(qa.y, off, 64);
            qa.z += __shfl_xor(qa.z, off, 64); qa.w += __shfl_xor(qa.w, off, 64);
            qb.x += __shfl_xor(qb.x, off, 64); qb.y += __shfl_xor(qb.y, off, 64);
            qb.z += __shfl_xor(qb.z, off, 64); qb.w += __shfl_xor(qb.w, off, 64);
        }
        if (lane < 8) {
            s_qp[item][side][wsub][2 * c8]     = qa;
            s_qp[item][side][wsub][2 * c8 + 1] = qb;
        }
    }
    __syncthreads();

    // ---- q = (masked mean) packed as half2; denom from counts ----
    if (tid8 < 128) {
        const int si = tid8 >> 6;
        const int dd = tid8 & 63;
        if (dd < 16) {
            const float dn = fmaxf((float)(s_cnt[item][si][0] + s_cnt[item][si][1]), 1.0f);
            const float rd = 1.0f / dn;
            const float4 q0 = s_qp[item][si][0][dd], q1 = s_qp[item][si][1][dd];
            s_qh[item][si][2 * dd]     = pack_h2((q0.x + q1.x) * rd, (q0.y + q1.y) * rd);
            s_qh[item][si][2 * dd + 1] = pack_h2((q0.z + q1.z) * rd, (q0.w + q1.w) * rd);
        }
    }
    __syncthreads();

    // ---- phase 3: scores from held regs (v_dot2) + feat prefetch
    //      (feat chunk at voff+128 in the fused row) ----
    {
        const uint4 qq = ((const uint4*)&s_qh[item][side][0])[c8];
        #pragma unroll
        for (int it = 0; it < 8; ++it) {
            const int g = 2 * it + wsub;
            if (g < G) {
                const int p = g * 8 + r8;
                const uint4 nf = *(const uint4*)((const char*)fused_table + voff[it] + 128);
                float sp = dot2acc(v[it].x, qq.x, 0.f);
                sp = dot2acc(v[it].y, qq.y, sp);
                sp = dot2acc(v[it].z, qq.z, sp);
                sp = dot2acc(v[it].w, qq.w, sp);
                #pragma unroll
                for (int off = 1; off <= 4; off <<= 1)
                    sp += __shfl_xor(sp, off, 64);   // reduce within 8-lane group
                if (c8 == 0 && p < nme) s_sc[item][side][p] = sp;
                v[it] = nf;
            }
        }
    }
    __syncthreads();

    // ---- phase 4: softmax over compacted scores (waves with wsub==0) ----
    if (wsub == 0) {
        const float s1 = (lane      < nme) ? s_sc[item][side][lane]      : -1e9f;
        const float s2 = (lane + 64 < nme) ? s_sc[item][side][lane + 64] : -1e9f;
        float mx = fmaxf(s1, s2);
        #pragma unroll
        for (int off = 32; off; off >>= 1) mx = fmaxf(mx, __shfl_xor(mx, off, 64));
        const float e1 = expf(s1 - mx), e2 = expf(s2 - mx);   // padding -> 0
        s_sc[item][side][lane] = e1; s_sc[item][side][lane + 64] = e2;
        float sm = e1 + e2;
        #pragma unroll
        for (int off = 32; off; off >>= 1) sm += __shfl_xor(sm, off, 64);
        if (lane == 0) s_sum[item][side] = sm;
    }
    __syncthreads();

    // ---- phase 5: attn-weighted sum from held feat regs ----
    {
        float4 oa = make_float4(0.f, 0.f, 0.f, 0.f);
        float4 ob = make_float4(0.f, 0.f, 0.f, 0.f);
        #pragma unroll
        for (int it = 0; it < 8; ++it) {
            const int g = 2 * it + wsub;
            if (g < G) {
                const int p = g * 8 + r8;
                const float w = (p < nme) ? s_sc[item][side][p] : 0.f;
                const float2 f0 = cvt2(v[it].x), f1 = cvt2(v[it].y);
                const float2 f2 = cvt2(v[it].z), f3 = cvt2(v[it].w);
                oa.x = fmaf(f0.x, w, oa.x); oa.y = fmaf(f0.y, w, oa.y);
                oa.z = fmaf(f1.x, w, oa.z); oa.w = fmaf(f1.y, w, oa.w);
                ob.x = fmaf(f2.x, w, ob.x); ob.y = fmaf(f2.y, w, ob.y);
                ob.z = fmaf(f3.x, w, ob.z); ob.w = fmaf(f3.y, w, ob.w);
            }
        }
        #pragma unroll
        for (int off = 8; off <= 32; off <<= 1) {
            oa.x += __shfl_xor(oa.x, off, 64); oa.y += __shfl_xor(oa.y, off, 64);
            oa.z += __shfl_xor(oa.z, off, 64); oa.w += __shfl_xor(oa.w, off, 64);
            ob.x += __shfl_xor(ob.x, off, 64); ob.y += __shfl_xor(ob.y, off, 64);
            ob.z += __shfl_xor(ob.z, off, 64); ob.w += __shfl_xor(ob.w, off, 64);
        }
        if (lane < 8) {
            s_op[item][side][wsub][2 * c8]     = oa;
            s_op[item][side][wsub][2 * c8 + 1] = ob;
        }
    }
    __syncthreads();

    // ---- combine halves -> mean vectors ----
    if (tid8 < 32) {
        const int si = tid8 >> 4, cc = tid8 & 15;
        const float inv = 1.0f / s_sum[item][si];
        const float4 o0 = s_op[item][si][0][cc], o1 = s_op[item][si][1][cc];
        float4 o;
        o.x = (o0.x + o1.x) * inv; o.y = (o0.y + o1.y) * inv;
        o.z = (o0.z + o1.z) * inv; o.w = (o0.w + o1.w) * inv;
        ((float4*)&s_mean[item][si][0])[cc] = o;
    }
    __syncthreads();

    // ---- cosine similarity * 5 (one wave per item) ----
    if (tid8 < 64) {
        const float a = s_mean[item][0][tid8], c = s_mean[item][1][tid8];
        float dt = a * c, na = a * a, nb = c * c;
        #pragma unroll
        for (int off = 32; off; off >>= 1) {
            dt += __shfl_xor(dt, off, 64);
            na += __shfl_xor(na, off, 64);
            nb += __shfl_xor(nb, off, 64);
        }
        if (tid8 == 0) {
            const float denom = fmaxf(sqrtf(na), 1e-8f) * fmaxf(sqrtf(nb), 1e-8f);
            out[b] = 5.0f * dt / denom;
        }
    }
}

extern "C" void kernel_launch(void* const* d_in, const int* in_sizes, int n_in,
                              void* d_out, int out_size, void* d_ws, size_t ws_size,
                              hipStream_t stream) {
    const int*   ids_a  = (const int*)d_in[0];
    const int*   mask_a = (const int*)d_in[1];
    const int*   ids_b  = (const int*)d_in[2];
    const int*   mask_b = (const int*)d_in[3];
    const float* mu     = (const float*)d_in[4];
    const float* feat   = (const float*)d_in[5];
    float* out = (float*)d_out;

    __half* ws_fused = (__half*)d_ws;   // V rows x 256 B (mu||feat) ~ 12.9 MB

    convert_fused_kernel<<<2048, 256, 0, stream>>>(mu, feat, ws_fused);
    softmax_attn_cos_kernel<<<NBLK, 512, 0, stream>>>(
        ids_a, mask_a, ids_b, mask_b, ws_fused, out);
}

// Round 6
// 113.908 us; speedup vs baseline: 1.0857x; 1.0406x over previous
//
#include <hip/hip_runtime.h>
#include <hip/hip_fp16.h>
#include <math.h>

// Problem constants (match reference)
#define BB 4096
#define LL 128
#define DD 64
#define VV 50257

typedef _Float16 h2_t __attribute__((ext_vector_type(2)));

// fp16x2 dot-accumulate: one v_dot2_f32_f16 where available.
__device__ __forceinline__ float dot2acc(unsigned a, unsigned b, float c) {
#if __has_builtin(__builtin_amdgcn_fdot2)
    return __builtin_amdgcn_fdot2(__builtin_bit_cast(h2_t, a),
                                  __builtin_bit_cast(h2_t, b), c, false);
#else
    const float2 fa = __half22float2(*(const __half2*)&a);
    const float2 fb = __half22float2(*(const __half2*)&b);
    return fmaf(fa.x, fb.x, fmaf(fa.y, fb.y, c));
#endif
}

__device__ __forceinline__ float2 cvt2(unsigned raw) {
    return __half22float2(*(const __half2*)&raw);
}

__device__ __forceinline__ unsigned pack_h2(float a, float b) {
    union { __half2 h; unsigned u; } p;
    p.h = __floats2half2_rn(a, b);
    return p.u;
}

// ---------------------------------------------------------------------------
// Kernel 1: stream-convert both fp32 tables into ONE fused fp16 table:
//   row id occupies 256 B = mu[id] (128 B) followed by feat[id] (128 B).
// ---------------------------------------------------------------------------
__global__ __launch_bounds__(256) void convert_fused_kernel(
    const float* __restrict__ mu, const float* __restrict__ feat,
    __half* __restrict__ out)
{
    const int total = VV * 16;              // 16-byte chunks in fused table
    for (int i = blockIdx.x * blockDim.x + threadIdx.x; i < total;
         i += gridDim.x * blockDim.x) {
        const int row = i >> 4;
        const int c   = i & 15;
        const float* src = (c < 8) ? (mu   + row * DD + c * 8)
                                   : (feat + row * DD + (c - 8) * 8);
        const float4 s0 = ((const float4*)src)[0];
        const float4 s1 = ((const float4*)src)[1];
        uint4 o;
        o.x = pack_h2(s0.x, s0.y); o.y = pack_h2(s0.z, s0.w);
        o.z = pack_h2(s1.x, s1.y); o.w = pack_h2(s1.z, s1.w);
        ((uint4*)out)[i] = o;               // byte offset i*16 == row*256 + c*16
    }
}

// ---------------------------------------------------------------------------
// Kernel 2: SERIAL-CHAIN-SHORTENED variant of the R0 structure.
// Same data path (mask compaction, two-round gather: mu held in v[8] with
// held voff[8], feat prefetched during score compute), but the barrier
// skeleton is cut from 8 __syncthreads to 5 and every narrow phase
// (q-mean 32-thr, softmax 128-thr, combine 32-thr, cos 64-thr) is either
// folded into a full-width phase via redundant per-wave computation
// (bitwise-identical shuffle trees) or fused into wave-0 registers.
// Arithmetic order preserved everywhere except the final cosine reduce.
// ---------------------------------------------------------------------------
__global__ __launch_bounds__(256, 6) void softmax_attn_cos_kernel(
    const int* __restrict__ ids_a, const int* __restrict__ mask_a,
    const int* __restrict__ ids_b, const int* __restrict__ mask_b,
    const __half* __restrict__ fused_table, float* __restrict__ out)
{
    __shared__ int      s_cid[2][LL];     // compacted unmasked ids
    __shared__ int      s_cnt[2][2];      // per-side, per-half unmasked counts
    __shared__ float4   s_qp[2][2][16];   // q partials
    __shared__ float    s_sc[2][LL];      // raw scores (never overwritten)
    __shared__ float    s_e[2][LL];       // exp weights (separate -> no race)
    __shared__ float4   s_op[2][2][16];   // output partials
    __shared__ float    s_sum[2];

    const int tid  = threadIdx.x;
    const int lane = tid & 63;
    const int wave = tid >> 6;        // 0..3
    const int side = wave >> 1;       // 0: a, 1: b
    const int wsub = wave & 1;        // which half (rows / groups parity)
    const int r8   = lane >> 3;       // 0..7 row subgroup
    const int c8   = lane & 7;        // 16-B chunk (8 halves) within a row
    const int b    = blockIdx.x;

    // ---- phase 1: load this wave's 64 rows; ballot-compact within wave ----
    {
        const int l = wsub * 64 + lane;
        const int* idp = side ? ids_b  : ids_a;
        const int* mp  = side ? mask_b : mask_a;
        const int id = idp[b * LL + l];
        const int m  = mp[b * LL + l];
        const unsigned long long bal = __ballot(m != 0);
        if (lane == 0) s_cnt[side][wsub] = __popcll(bal);
        const int rank = __popcll(bal & ((1ull << lane) - 1ull));
        __syncthreads();                               // barrier 1
        const int offset = wsub ? s_cnt[side][0] : 0;
        if (m) s_cid[side][offset + rank] = id;
        if (s_cnt[side][0] + s_cnt[side][1] == 0)
            s_cid[side][l] = id;                       // all-masked fallback
    }
    __syncthreads();                                   // barrier 2

    const int   nm  = s_cnt[side][0] + s_cnt[side][1];
    const int   nme = (nm == 0) ? 128 : nm;            // effective length
    const int   G   = (nme + 7) >> 3;                  // 8-row groups

    // ---- phase 2: gather compacted mu half-rows (held voff), q partials;
    //      wave-uniform skip of groups >= G ----
    uint4 v[8];
    unsigned voff[8];
    {
        float4 qa = make_float4(0.f, 0.f, 0.f, 0.f);
        float4 qb = make_float4(0.f, 0.f, 0.f, 0.f);
        #pragma unroll
        for (int it = 0; it < 8; ++it) {
            v[it] = make_uint4(0u, 0u, 0u, 0u);
            voff[it] = 0u;
            const int g = 2 * it + wsub;
            if (g < G) {                               // wave-uniform branch
                const int p  = g * 8 + r8;
                const int id = (p < nme) ? s_cid[side][p] : 0;
                voff[it] = ((unsigned)id << 8) + ((unsigned)c8 << 4);
                v[it] = *(const uint4*)((const char*)fused_table + voff[it]);
                if (p < nm) {                          // live rows only
                    const float2 f0 = cvt2(v[it].x), f1 = cvt2(v[it].y);
                    const float2 f2 = cvt2(v[it].z), f3 = cvt2(v[it].w);
                    qa.x += f0.x; qa.y += f0.y; qa.z += f1.x; qa.w += f1.y;
                    qb.x += f2.x; qb.y += f2.y; qb.z += f3.x; qb.w += f3.y;
                }
            }
        }
        #pragma unroll
        for (int off = 8; off <= 32; off <<= 1) {      // sum the 8 row-groups
            qa.x += __shfl_xor(qa.x, off, 64); qa.y += __shfl_xor(qa.y, off, 64);
            qa.z += __shfl_xor(qa.z, off, 64); qa.w += __shfl_xor(qa.w, off, 64);
            qb.x += __shfl_xor(qb.x, off, 64); qb.y += __shfl_xor(qb.y, off, 64);
            qb.z += __shfl_xor(qb.z, off, 64); qb.w += __shfl_xor(qb.w, off, 64);
        }
        if (lane < 8) {
            s_qp[side][wsub][2 * c8]     = qa;
            s_qp[side][wsub][2 * c8 + 1] = qb;
        }
    }
    __syncthreads();                                   // barrier 3

    // ---- phase 3: per-lane q-mean fold (redundant, bitwise-identical to
    //      the old 16-thread phase), then scores + feat prefetch ----
    {
        const float dn = fmaxf((float)(s_cnt[side][0] + s_cnt[side][1]), 1.0f);
        const float rd = 1.0f / dn;
        const float4 q0a = s_qp[side][0][2 * c8],     q1a = s_qp[side][1][2 * c8];
        const float4 q0b = s_qp[side][0][2 * c8 + 1], q1b = s_qp[side][1][2 * c8 + 1];
        uint4 qq;
        qq.x = pack_h2((q0a.x + q1a.x) * rd, (q0a.y + q1a.y) * rd);
        qq.y = pack_h2((q0a.z + q1a.z) * rd, (q0a.w + q1a.w) * rd);
        qq.z = pack_h2((q0b.x + q1b.x) * rd, (q0b.y + q1b.y) * rd);
        qq.w = pack_h2((q0b.z + q1b.z) * rd, (q0b.w + q1b.w) * rd);

        #pragma unroll
        for (int it = 0; it < 8; ++it) {
            const int g = 2 * it + wsub;
            if (g < G) {
                const int p = g * 8 + r8;
                const uint4 nf = *(const uint4*)((const char*)fused_table + voff[it] + 128);
                float sp = dot2acc(v[it].x, qq.x, 0.f);
                sp = dot2acc(v[it].y, qq.y, sp);
                sp = dot2acc(v[it].z, qq.z, sp);
                sp = dot2acc(v[it].w, qq.w, sp);
                #pragma unroll
                for (int off = 1; off <= 4; off <<= 1)
                    sp += __shfl_xor(sp, off, 64);     // reduce 8-lane group
                if (c8 == 0 && p < nme) s_sc[side][p] = sp;
                v[it] = nf;                            // feat now held
            }
        }
    }
    __syncthreads();                                   // barrier 4

    // ---- phase 5 (softmax folded in): every wave redundantly reduces the
    //      raw scores (identical shuffle tree -> bitwise-identical mx, sm),
    //      writes exp weights to its own-covered s_e, then accumulates ----
    {
        const float s1 = (lane      < nme) ? s_sc[side][lane]      : -1e9f;
        const float s2 = (lane + 64 < nme) ? s_sc[side][lane + 64] : -1e9f;
        float mx = fmaxf(s1, s2);
        #pragma unroll
        for (int off = 32; off; off >>= 1) mx = fmaxf(mx, __shfl_xor(mx, off, 64));
        const float e1 = expf(s1 - mx), e2 = expf(s2 - mx);   // padding -> 0
        s_e[side][lane] = e1; s_e[side][lane + 64] = e2;      // own wave covers all 128
        float sm = e1 + e2;
        #pragma unroll
        for (int off = 32; off; off >>= 1) sm += __shfl_xor(sm, off, 64);
        if (lane == 0) s_sum[side] = sm;      // both waves write identical value

        float4 oa = make_float4(0.f, 0.f, 0.f, 0.f);
        float4 ob = make_float4(0.f, 0.f, 0.f, 0.f);
        #pragma unroll
        for (int it = 0; it < 8; ++it) {
            const int g = 2 * it + wsub;
            if (g < G) {
                const int p = g * 8 + r8;
                const float w = (p < nme) ? s_e[side][p] : 0.f;  // wave-local LDS
                const float2 f0 = cvt2(v[it].x), f1 = cvt2(v[it].y);
                const float2 f2 = cvt2(v[it].z), f3 = cvt2(v[it].w);
                oa.x = fmaf(f0.x, w, oa.x); oa.y = fmaf(f0.y, w, oa.y);
                oa.z = fmaf(f1.x, w, oa.z); oa.w = fmaf(f1.y, w, oa.w);
                ob.x = fmaf(f2.x, w, ob.x); ob.y = fmaf(f2.y, w, ob.y);
                ob.z = fmaf(f3.x, w, ob.z); ob.w = fmaf(f3.y, w, ob.w);
            }
        }
        #pragma unroll
        for (int off = 8; off <= 32; off <<= 1) {
            oa.x += __shfl_xor(oa.x, off, 64); oa.y += __shfl_xor(oa.y, off, 64);
            oa.z += __shfl_xor(oa.z, off, 64); oa.w += __shfl_xor(oa.w, off, 64);
            ob.x += __shfl_xor(ob.x, off, 64); ob.y += __shfl_xor(ob.y, off, 64);
            ob.z += __shfl_xor(ob.z, off, 64); ob.w += __shfl_xor(ob.w, off, 64);
        }
        if (lane < 8) {
            s_op[side][wsub][2 * c8]     = oa;
            s_op[side][wsub][2 * c8 + 1] = ob;
        }
    }
    __syncthreads();                                   // barrier 5

    // ---- fused combine + cosine, entirely in wave 0 registers ----
    if (wave == 0) {
        const int t  = lane & 31;          // lanes 32-63 mirror 0-31 (unused)
        const int si = t >> 4, cc = t & 15;
        const float inv = 1.0f / s_sum[si];
        const float4 o0 = s_op[si][0][cc], o1 = s_op[si][1][cc];
        float4 o;
        o.x = (o0.x + o1.x) * inv; o.y = (o0.y + o1.y) * inv;
        o.z = (o0.z + o1.z) * inv; o.w = (o0.w + o1.w) * inv;
        // lanes 0-15 hold side-a dims (cc*4..+3); partner lane t+16 holds side-b
        const float cx = __shfl(o.x, t + 16, 64);
        const float cy = __shfl(o.y, t + 16, 64);
        const float cz = __shfl(o.z, t + 16, 64);
        const float cw = __shfl(o.w, t + 16, 64);
        float dt = o.x * cx + o.y * cy + o.z * cz + o.w * cw;
        float na = o.x * o.x + o.y * o.y + o.z * o.z + o.w * o.w;
        float nb = cx * cx + cy * cy + cz * cz + cw * cw;
        #pragma unroll
        for (int off = 1; off <= 8; off <<= 1) {
            dt += __shfl_xor(dt, off, 64);
            na += __shfl_xor(na, off, 64);
            nb += __shfl_xor(nb, off, 64);
        }
        if (lane == 0) {
            const float denom = fmaxf(sqrtf(na), 1e-8f) * fmaxf(sqrtf(nb), 1e-8f);
            out[b] = 5.0f * dt / denom;
        }
    }
}

extern "C" void kernel_launch(void* const* d_in, const int* in_sizes, int n_in,
                              void* d_out, int out_size, void* d_ws, size_t ws_size,
                              hipStream_t stream) {
    const int*   ids_a  = (const int*)d_in[0];
    const int*   mask_a = (const int*)d_in[1];
    const int*   ids_b  = (const int*)d_in[2];
    const int*   mask_b = (const int*)d_in[3];
    const float* mu     = (const float*)d_in[4];
    const float* feat   = (const float*)d_in[5];
    float* out = (float*)d_out;

    __half* ws_fused = (__half*)d_ws;   // V rows x 256 B (mu||feat) ~ 12.9 MB

    convert_fused_kernel<<<2048, 256, 0, stream>>>(mu, feat, ws_fused);
    softmax_attn_cos_kernel<<<BB, 256, 0, stream>>>(
        ids_a, mask_a, ids_b, mask_b, ws_fused, out);
}

// Round 7
// 112.713 us; speedup vs baseline: 1.0972x; 1.0106x over previous
//
#include <hip/hip_runtime.h>
#include <hip/hip_fp16.h>
#include <math.h>

// Problem constants (match reference)
#define BB 4096
#define LL 128
#define DD 64
#define VV 50257

typedef _Float16 h2_t __attribute__((ext_vector_type(2)));

// fp16x2 dot-accumulate: one v_dot2_f32_f16 where available.
__device__ __forceinline__ float dot2acc(unsigned a, unsigned b, float c) {
#if __has_builtin(__builtin_amdgcn_fdot2)
    return __builtin_amdgcn_fdot2(__builtin_bit_cast(h2_t, a),
                                  __builtin_bit_cast(h2_t, b), c, false);
#else
    const float2 fa = __half22float2(*(const __half2*)&a);
    const float2 fb = __half22float2(*(const __half2*)&b);
    return fmaf(fa.x, fb.x, fmaf(fa.y, fb.y, c));
#endif
}

__device__ __forceinline__ float2 cvt2(unsigned raw) {
    return __half22float2(*(const __half2*)&raw);
}

__device__ __forceinline__ unsigned pack_h2(float a, float b) {
    union { __half2 h; unsigned u; } p;
    p.h = __floats2half2_rn(a, b);
    return p.u;
}

// ---------------------------------------------------------------------------
// Kernel 1: stream-convert both fp32 tables into ONE fused fp16 table:
//   row id occupies 256 B = mu[id] (128 B) followed by feat[id] (128 B).
// ---------------------------------------------------------------------------
__global__ __launch_bounds__(256) void convert_fused_kernel(
    const float* __restrict__ mu, const float* __restrict__ feat,
    __half* __restrict__ out)
{
    const int total = VV * 16;              // 16-byte chunks in fused table
    for (int i = blockIdx.x * blockDim.x + threadIdx.x; i < total;
         i += gridDim.x * blockDim.x) {
        const int row = i >> 4;
        const int c   = i & 15;
        const float* src = (c < 8) ? (mu   + row * DD + c * 8)
                                   : (feat + row * DD + (c - 8) * 8);
        const float4 s0 = ((const float4*)src)[0];
        const float4 s1 = ((const float4*)src)[1];
        uint4 o;
        o.x = pack_h2(s0.x, s0.y); o.y = pack_h2(s0.z, s0.w);
        o.z = pack_h2(s1.x, s1.y); o.w = pack_h2(s1.z, s1.w);
        ((uint4*)out)[i] = o;               // byte offset i*16 == row*256 + c*16
    }
}

// ---------------------------------------------------------------------------
// Kernel 2: COMBINATION round — R1's single-round deep-MLP gather (all 16
// mu+feat loads issued up-front per thread, 256-B contiguous per row; proven
// 56-VGPR codegen, no spill) x R6's 5-barrier wide-phase skeleton (q-mean
// folded per-lane, softmax folded per-wave into s_e, fused wave-0 epilogue).
// Each lever alone sat inside the +-3-5us total-noise band; R2's 2.27 TB/s
// L2-fill demonstration says their combination should push the fp16 gather
// toward ~31us service-bound if the latency-concurrency model is right.
// Arithmetic identical to all passing rounds except the final cos reduce.
// ---------------------------------------------------------------------------
__global__ __launch_bounds__(256, 4) void softmax_attn_cos_kernel(
    const int* __restrict__ ids_a, const int* __restrict__ mask_a,
    const int* __restrict__ ids_b, const int* __restrict__ mask_b,
    const __half* __restrict__ fused_table, float* __restrict__ out)
{
    __shared__ int      s_cid[2][LL];     // compacted unmasked ids
    __shared__ int      s_cnt[2][2];      // per-side, per-half unmasked counts
    __shared__ float4   s_qp[2][2][16];   // q partials
    __shared__ float    s_sc[2][LL];      // raw scores (never overwritten)
    __shared__ float    s_e[2][LL];       // exp weights (separate -> no race)
    __shared__ float4   s_op[2][2][16];   // output partials
    __shared__ float    s_sum[2];

    const int tid  = threadIdx.x;
    const int lane = tid & 63;
    const int wave = tid >> 6;        // 0..3
    const int side = wave >> 1;       // 0: a, 1: b
    const int wsub = wave & 1;        // which half (rows / groups parity)
    const int r8   = lane >> 3;       // 0..7 row subgroup
    const int c8   = lane & 7;        // 16-B chunk (8 halves) within a row
    const int b    = blockIdx.x;

    // ---- phase 1: load this wave's 64 rows; ballot-compact within wave ----
    {
        const int l = wsub * 64 + lane;
        const int* idp = side ? ids_b  : ids_a;
        const int* mp  = side ? mask_b : mask_a;
        const int id = idp[b * LL + l];
        const int m  = mp[b * LL + l];
        const unsigned long long bal = __ballot(m != 0);
        if (lane == 0) s_cnt[side][wsub] = __popcll(bal);
        const int rank = __popcll(bal & ((1ull << lane) - 1ull));
        __syncthreads();                               // barrier 1
        const int offset = wsub ? s_cnt[side][0] : 0;
        if (m) s_cid[side][offset + rank] = id;
        if (s_cnt[side][0] + s_cnt[side][1] == 0)
            s_cid[side][l] = id;                       // all-masked fallback
    }
    __syncthreads();                                   // barrier 2

    const int   nm  = s_cnt[side][0] + s_cnt[side][1];
    const int   nme = (nm == 0) ? 128 : nm;            // effective length
    const int   G   = (nme + 7) >> 3;                  // 8-row groups

    // ---- phase 2: SINGLE gather round — issue all mu+feat loads first
    //      (16 in flight per thread, 256-B contiguous per row), then
    //      q-accumulation; wave-uniform group skip ----
    uint4 v[8];   // mu chunks   (consumed by scores, phase 3)
    uint4 f[8];   // feat chunks (consumed by weighted sum, phase 4)
    {
        #pragma unroll
        for (int it = 0; it < 8; ++it) {
            v[it] = make_uint4(0u, 0u, 0u, 0u);
            f[it] = make_uint4(0u, 0u, 0u, 0u);
            const int g = 2 * it + wsub;
            if (g < G) {                               // wave-uniform branch
                const int p  = g * 8 + r8;
                const int id = (p < nme) ? s_cid[side][p] : 0;
                const char* base = (const char*)fused_table
                                 + ((unsigned)id << 8) + ((unsigned)c8 << 4);
                v[it] = *(const uint4*)(base);         // mu chunk
                f[it] = *(const uint4*)(base + 128);   // feat chunk
            }
        }
        float4 qa = make_float4(0.f, 0.f, 0.f, 0.f);
        float4 qb = make_float4(0.f, 0.f, 0.f, 0.f);
        #pragma unroll
        for (int it = 0; it < 8; ++it) {
            const int g = 2 * it + wsub;
            const int p = g * 8 + r8;
            if (g < G && p < nm) {                     // live rows only
                const float2 f0 = cvt2(v[it].x), f1 = cvt2(v[it].y);
                const float2 f2 = cvt2(v[it].z), f3 = cvt2(v[it].w);
                qa.x += f0.x; qa.y += f0.y; qa.z += f1.x; qa.w += f1.y;
                qb.x += f2.x; qb.y += f2.y; qb.z += f3.x; qb.w += f3.y;
            }
        }
        #pragma unroll
        for (int off = 8; off <= 32; off <<= 1) {      // sum the 8 row-groups
            qa.x += __shfl_xor(qa.x, off, 64); qa.y += __shfl_xor(qa.y, off, 64);
            qa.z += __shfl_xor(qa.z, off, 64); qa.w += __shfl_xor(qa.w, off, 64);
            qb.x += __shfl_xor(qb.x, off, 64); qb.y += __shfl_xor(qb.y, off, 64);
            qb.z += __shfl_xor(qb.z, off, 64); qb.w += __shfl_xor(qb.w, off, 64);
        }
        if (lane < 8) {
            s_qp[side][wsub][2 * c8]     = qa;
            s_qp[side][wsub][2 * c8 + 1] = qb;
        }
    }
    __syncthreads();                                   // barrier 3

    // ---- phase 3: per-lane q-mean fold (redundant, bitwise-identical),
    //      then scores from held mu regs (pure compute) ----
    {
        const float dn = fmaxf((float)(s_cnt[side][0] + s_cnt[side][1]), 1.0f);
        const float rd = 1.0f / dn;
        const float4 q0a = s_qp[side][0][2 * c8],     q1a = s_qp[side][1][2 * c8];
        const float4 q0b = s_qp[side][0][2 * c8 + 1], q1b = s_qp[side][1][2 * c8 + 1];
        uint4 qq;
        qq.x = pack_h2((q0a.x + q1a.x) * rd, (q0a.y + q1a.y) * rd);
        qq.y = pack_h2((q0a.z + q1a.z) * rd, (q0a.w + q1a.w) * rd);
        qq.z = pack_h2((q0b.x + q1b.x) * rd, (q0b.y + q1b.y) * rd);
        qq.w = pack_h2((q0b.z + q1b.z) * rd, (q0b.w + q1b.w) * rd);

        #pragma unroll
        for (int it = 0; it < 8; ++it) {
            const int g = 2 * it + wsub;
            if (g < G) {
                const int p = g * 8 + r8;
                float sp = dot2acc(v[it].x, qq.x, 0.f);
                sp = dot2acc(v[it].y, qq.y, sp);
                sp = dot2acc(v[it].z, qq.z, sp);
                sp = dot2acc(v[it].w, qq.w, sp);
                #pragma unroll
                for (int off = 1; off <= 4; off <<= 1)
                    sp += __shfl_xor(sp, off, 64);     // reduce 8-lane group
                if (c8 == 0 && p < nme) s_sc[side][p] = sp;
            }
        }
    }
    __syncthreads();                                   // barrier 4

    // ---- phase 4: softmax folded per-wave (bitwise-identical shuffle
    //      trees), then weighted sum from held feat regs ----
    {
        const float s1 = (lane      < nme) ? s_sc[side][lane]      : -1e9f;
        const float s2 = (lane + 64 < nme) ? s_sc[side][lane + 64] : -1e9f;
        float mx = fmaxf(s1, s2);
        #pragma unroll
        for (int off = 32; off; off >>= 1) mx = fmaxf(mx, __shfl_xor(mx, off, 64));
        const float e1 = expf(s1 - mx), e2 = expf(s2 - mx);   // padding -> 0
        s_e[side][lane] = e1; s_e[side][lane + 64] = e2;      // own wave covers 128
        float sm = e1 + e2;
        #pragma unroll
        for (int off = 32; off; off >>= 1) sm += __shfl_xor(sm, off, 64);
        if (lane == 0) s_sum[side] = sm;       // both waves write same value

        float4 oa = make_float4(0.f, 0.f, 0.f, 0.f);
        float4 ob = make_float4(0.f, 0.f, 0.f, 0.f);
        #pragma unroll
        for (int it = 0; it < 8; ++it) {
            const int g = 2 * it + wsub;
            if (g < G) {
                const int p = g * 8 + r8;
                const float w = (p < nme) ? s_e[side][p] : 0.f;  // wave-local
                const float2 f0 = cvt2(f[it].x), f1 = cvt2(f[it].y);
                const float2 f2 = cvt2(f[it].z), f3 = cvt2(f[it].w);
                oa.x = fmaf(f0.x, w, oa.x); oa.y = fmaf(f0.y, w, oa.y);
                oa.z = fmaf(f1.x, w, oa.z); oa.w = fmaf(f1.y, w, oa.w);
                ob.x = fmaf(f2.x, w, ob.x); ob.y = fmaf(f2.y, w, ob.y);
                ob.z = fmaf(f3.x, w, ob.z); ob.w = fmaf(f3.y, w, ob.w);
            }
        }
        #pragma unroll
        for (int off = 8; off <= 32; off <<= 1) {
            oa.x += __shfl_xor(oa.x, off, 64); oa.y += __shfl_xor(oa.y, off, 64);
            oa.z += __shfl_xor(oa.z, off, 64); oa.w += __shfl_xor(oa.w, off, 64);
            ob.x += __shfl_xor(ob.x, off, 64); ob.y += __shfl_xor(ob.y, off, 64);
            ob.z += __shfl_xor(ob.z, off, 64); ob.w += __shfl_xor(ob.w, off, 64);
        }
        if (lane < 8) {
            s_op[side][wsub][2 * c8]     = oa;
            s_op[side][wsub][2 * c8 + 1] = ob;
        }
    }
    __syncthreads();                                   // barrier 5

    // ---- fused combine + cosine, entirely in wave 0 registers ----
    if (wave == 0) {
        const int t  = lane & 31;          // lanes 32-63 mirror 0-31 (unused)
        const int si = t >> 4, cc = t & 15;
        const float inv = 1.0f / s_sum[si];
        const float4 o0 = s_op[si][0][cc], o1 = s_op[si][1][cc];
        float4 o;
        o.x = (o0.x + o1.x) * inv; o.y = (o0.y + o1.y) * inv;
        o.z = (o0.z + o1.z) * inv; o.w = (o0.w + o1.w) * inv;
        // lanes 0-15 hold side-a dims (cc*4..+3); partner lane t+16 holds side-b
        const float cx = __shfl(o.x, t + 16, 64);
        const float cy = __shfl(o.y, t + 16, 64);
        const float cz = __shfl(o.z, t + 16, 64);
        const float cw = __shfl(o.w, t + 16, 64);
        float dt = o.x * cx + o.y * cy + o.z * cz + o.w * cw;
        float na = o.x * o.x + o.y * o.y + o.z * o.z + o.w * o.w;
        float nb = cx * cx + cy * cy + cz * cz + cw * cw;
        #pragma unroll
        for (int off = 1; off <= 8; off <<= 1) {
            dt += __shfl_xor(dt, off, 64);
            na += __shfl_xor(na, off, 64);
            nb += __shfl_xor(nb, off, 64);
        }
        if (lane == 0) {
            const float denom = fmaxf(sqrtf(na), 1e-8f) * fmaxf(sqrtf(nb), 1e-8f);
            out[b] = 5.0f * dt / denom;
        }
    }
}

extern "C" void kernel_launch(void* const* d_in, const int* in_sizes, int n_in,
                              void* d_out, int out_size, void* d_ws, size_t ws_size,
                              hipStream_t stream) {
    const int*   ids_a  = (const int*)d_in[0];
    const int*   mask_a = (const int*)d_in[1];
    const int*   ids_b  = (const int*)d_in[2];
    const int*   mask_b = (const int*)d_in[3];
    const float* mu     = (const float*)d_in[4];
    const float* feat   = (const float*)d_in[5];
    float* out = (float*)d_out;

    __half* ws_fused = (__half*)d_ws;   // V rows x 256 B (mu||feat) ~ 12.9 MB

    convert_fused_kernel<<<2048, 256, 0, stream>>>(mu, feat, ws_fused);
    softmax_attn_cos_kernel<<<BB, 256, 0, stream>>>(
        ids_a, mask_a, ids_b, mask_b, ws_fused, out);
}